// Round 3
// baseline (753.328 us; speedup 1.0000x reference)
//
#include <hip/hip_runtime.h>
#include <hip/hip_bf16.h>

namespace {

constexpr int T = 1024;
constexpr int B = 1024;
constexpr int L = 10;
constexpr int H = 10;
constexpr int BBLK = 4;                  // batch elements per block
constexpr int NTHREADS = L * BBLK * H;   // 400 threads

// v_exp-based fast activations; saturation-safe at +/-inf.
__device__ __forceinline__ float sigmoid_f(float x) {
    return __builtin_amdgcn_rcpf(1.0f + __expf(-x));
}
__device__ __forceinline__ float tanh_f(float x) {
    // tanh(x) = 1 - 2/(exp(2x)+1); exp->inf gives 1, exp->0 gives -1.
    return 1.0f - 2.0f * __builtin_amdgcn_rcpf(1.0f + __expf(2.0f * x));
}

__global__ __launch_bounds__(NTHREADS) void lstm_pipeline(
    const float* __restrict__ x,    // [T,B,H] fp32
    const float* __restrict__ hp,   // [L,B,H] fp32
    const float* __restrict__ cp,   // [L,B,H] fp32
    const float* __restrict__ Wih,  // [L,4H,H] fp32
    const float* __restrict__ Whh,  // [L,4H,H] fp32
    const float* __restrict__ bih,  // [L,4H] fp32
    const float* __restrict__ bhh,  // [L,4H] fp32
    float* __restrict__ out,        // [T,B,H] fp32
    float* __restrict__ hn,         // [L,B,H] fp32
    float* __restrict__ cn)         // [L,B,H] fp32
{
    // buf[l] = input to layer l (l=0: staged x; l>=1: h of layer l-1).
    // Double-buffered on parity of t; padded 10->12 floats for float4 reads.
    __shared__ __align__(16) float buf[L + 1][2][BBLK][12];

    const int tid = threadIdx.x;
    const int l  = tid / (BBLK * H);   // layer         0..9
    const int r  = tid % (BBLK * H);
    const int bl = r / H;              // local batch   0..3
    const int j  = r % H;              // hidden unit   0..9
    const int b  = blockIdx.x * BBLK + bl;

    // Per-thread weights: rows {j, H+j, 2H+j, 3H+j} of this layer's W (gate order i,f,g,o).
    float wi[4][H], wh[4][H], bias[4];
    #pragma unroll
    for (int g = 0; g < 4; ++g) {
        const int row = g * H + j;
        #pragma unroll
        for (int i = 0; i < H; ++i) {
            wi[g][i] = Wih[(l * 4 * H + row) * H + i];
            wh[g][i] = Whh[(l * 4 * H + row) * H + i];
        }
        bias[g] = bih[l * 4 * H + row] + bhh[l * 4 * H + row];
    }

    float c = cp[(l * B + b) * H + j];
    // h(-1) lives in parity slot 1 (t=0 reads parity (t-1)&1 == 1).
    buf[l + 1][1][bl][j] = hp[(l * B + b) * H + j];

    // Layer-0 x register pipe: xa = x(1) (written to LDS at s=0),
    // xb = x(2) in flight. t=0's x staged directly.
    float xa = 0.0f, xb = 0.0f;
    if (l == 0) {
        const int off = b * H + j;
        buf[0][0][bl][j] = x[off];                    // x(t=0)
        xa = x[(size_t)1 * (B * H) + off];
        xb = x[(size_t)2 * (B * H) + off];
    }
    __syncthreads();

    // Diagonal pipeline: at vstep s, layer l processes t = s - l.
    for (int s = 0; s < T + L - 1; ++s) {
        const int t = s - l;
        if (t >= 0 && t < T) {
            const int p  = t & 1;
            const int pm = (t - 1) & 1;  // (-1)&1 == 1
            float xin[12], hin[12];
            {
                float4* xv = (float4*)xin;
                float4* hv = (float4*)hin;
                const float4* xs = (const float4*)&buf[l][p][bl][0];
                const float4* hs = (const float4*)&buf[l + 1][pm][bl][0];
                xv[0] = xs[0]; xv[1] = xs[1]; xv[2] = xs[2];
                hv[0] = hs[0]; hv[1] = hs[1]; hv[2] = hs[2];
            }

            float acc[4] = {bias[0], bias[1], bias[2], bias[3]};
            #pragma unroll
            for (int i = 0; i < H; ++i) {
                #pragma unroll
                for (int g = 0; g < 4; ++g) acc[g] = fmaf(wi[g][i], xin[i], acc[g]);
            }
            #pragma unroll
            for (int k = 0; k < H; ++k) {
                #pragma unroll
                for (int g = 0; g < 4; ++g) acc[g] = fmaf(wh[g][k], hin[k], acc[g]);
            }

            const float ig = sigmoid_f(acc[0]);
            const float fg = sigmoid_f(acc[1]);
            const float gg = tanh_f(acc[2]);
            const float og = sigmoid_f(acc[3]);
            c = fmaf(fg, c, ig * gg);
            const float hval = og * tanh_f(c);

            buf[l + 1][p][bl][j] = hval;
            if (l == L - 1) {
                out[(size_t)t * (B * H) + b * H + j] = hval;
            }
        }
        // Layer-0 threads stage x(s+1) (loaded >=1 vstep ago) and issue x(s+3).
        if (l == 0 && (s + 1) < T) {
            buf[0][(s + 1) & 1][bl][j] = xa;
            xa = xb;
            if ((s + 3) < T) {
                xb = x[(size_t)(s + 3) * (B * H) + b * H + j];
            }
        }
        __syncthreads();
    }

    // Finals: h_l(T-1) is this thread's own last write; c is in-register.
    hn[(l * B + b) * H + j] = buf[l + 1][(T - 1) & 1][bl][j];
    cn[(l * B + b) * H + j] = c;
}

} // namespace

extern "C" void kernel_launch(void* const* d_in, const int* in_sizes, int n_in,
                              void* d_out, int out_size, void* d_ws, size_t ws_size,
                              hipStream_t stream) {
    (void)in_sizes; (void)n_in; (void)d_ws; (void)ws_size; (void)out_size;
    const float* x   = (const float*)d_in[0];
    const float* hp  = (const float*)d_in[1];
    const float* cp  = (const float*)d_in[2];
    const float* Wih = (const float*)d_in[3];
    const float* Whh = (const float*)d_in[4];
    const float* bih = (const float*)d_in[5];
    const float* bhh = (const float*)d_in[6];

    float* out = (float*)d_out;
    float* hn  = out + (size_t)T * B * H;
    float* cn  = hn + (size_t)L * B * H;

    lstm_pipeline<<<dim3(B / BBLK), dim3(NTHREADS), 0, stream>>>(
        x, hp, cp, Wih, Whh, bih, bhh, out, hn, cn);
}

// Round 4
// 545.628 us; speedup vs baseline: 1.3807x; 1.3807x over previous
//
#include <hip/hip_runtime.h>

namespace {

constexpr int T = 1024;
constexpr int B = 1024;
constexpr int L = 10;
constexpr int H = 10;
constexpr int BBLK = 4;                  // batch elements per block
constexpr int NTHREADS = L * BBLK * H;   // 400 threads
constexpr int CH = 8;                    // vsteps per chunk (drain-amortization)
constexpr int BH = B * H;
constexpr int NSTEP = T + L - 1;                  // 1033
constexpr int NCHUNK = (NSTEP + CH - 1) / CH;     // 130

// v_exp-based fast activations; saturation-safe at +/-inf.
__device__ __forceinline__ float sigmoid_f(float x) {
    return __builtin_amdgcn_rcpf(1.0f + __expf(-x));
}
__device__ __forceinline__ float tanh_f(float x) {
    // tanh(x) = 1 - 2/(exp(2x)+1); exp->inf gives 1, exp->0 gives -1.
    return 1.0f - 2.0f * __builtin_amdgcn_rcpf(1.0f + __expf(2.0f * x));
}

// __launch_bounds__(400, 1): min 1 wave/EU frees the allocator to keep the
// 84-float per-thread weight set in VGPRs (round-3 showed VGPR_Count=64 ->
// weights were being reloaded from L2 inside the step loop).
__global__ __launch_bounds__(NTHREADS, 1) void lstm_pipeline(
    const float* __restrict__ x,    // [T,B,H]
    const float* __restrict__ hp,   // [L,B,H]
    const float* __restrict__ cp,   // [L,B,H]
    const float* __restrict__ Wih,  // [L,4H,H]
    const float* __restrict__ Whh,  // [L,4H,H]
    const float* __restrict__ bih,  // [L,4H]
    const float* __restrict__ bhh,  // [L,4H]
    float* __restrict__ out,        // [T,B,H]
    float* __restrict__ hn,         // [L,B,H]
    float* __restrict__ cn)         // [L,B,H]
{
    // buf[l] = input to layer l (l=0: staged x; l>=1: h of layer l-1).
    // s-parity double buffering: anything written at vstep s goes to slot
    // s&1 and is read at vstep s+1 from slot (s+1-1)&1 = s&1. With CH even
    // and chunks starting at even s, parities are compile-time in the
    // unrolled chunk body. Rows padded 10->12 floats for float4 reads.
    __shared__ __align__(16) float buf[L + 1][2][BBLK][12];

    const int tid = threadIdx.x;
    const int l  = tid / (BBLK * H);   // layer         0..9
    const int r  = tid % (BBLK * H);
    const int bl = r / H;              // local batch   0..3
    const int j  = r % H;              // hidden unit   0..9
    const int b  = blockIdx.x * BBLK + bl;
    const int boff = b * H + j;

    // Per-thread weights: rows {j, H+j, 2H+j, 3H+j} of this layer's W
    // (torch gate order i, f, g, o).
    float wi[4][H], wh[4][H], bias[4];
    #pragma unroll
    for (int g = 0; g < 4; ++g) {
        const int row = g * H + j;
        #pragma unroll
        for (int i = 0; i < H; ++i) {
            wi[g][i] = Wih[(l * 4 * H + row) * H + i];
            wh[g][i] = Whh[(l * 4 * H + row) * H + i];
        }
        bias[g] = bih[l * 4 * H + row] + bhh[l * 4 * H + row];
    }

    float c = cp[(l * B + b) * H + j];
    // h(-1) is read by layer l at s=l from parity (l-1)&1.
    buf[l + 1][(l & 1) ^ 1][bl][j] = hp[(l * B + b) * H + j];

    // Layer-0 x pipe: xcur = x(t) for t = s0+1..s0+CH (staged this chunk),
    // xnext = next chunk's, loads issued at chunk top (drain once/chunk).
    float xcur[CH], xnext[CH], hbuf[CH];
    if (l == 0) {
        buf[0][1][bl][j] = x[boff];               // x(0), read at s=0 parity 1
        #pragma unroll
        for (int i = 0; i < CH; ++i) xcur[i] = x[(size_t)(1 + i) * BH + boff];
    }
    __syncthreads();

    for (int k = 0; k < NCHUNK; ++k) {
        const int s0 = k * CH;

        // Issue next chunk's x loads now; the forced vmcnt(0) at the u=0
        // barrier absorbs their latency once per CH steps.
        if (l == 0) {
            #pragma unroll
            for (int i = 0; i < CH; ++i) {
                int t = s0 + CH + 1 + i;
                t = t < T ? t : T - 1;            // clamp; never staged if OOB
                xnext[i] = x[(size_t)t * BH + boff];
            }
        }

        #pragma unroll
        for (int u = 0; u < CH; ++u) {
            const int s = s0 + u;
            const int t = s - l;
            constexpr int UNUSED = 0; (void)UNUSED;
            const int wp = u & 1;                 // s&1 (s0 even)
            const int rp = wp ^ 1;                // (s-1)&1

            if (t >= 0 && t < T) {
                float xin[12], hin[12];
                {
                    float4* xv = (float4*)xin;
                    float4* hv = (float4*)hin;
                    const float4* xs = (const float4*)&buf[l][rp][bl][0];
                    const float4* hs = (const float4*)&buf[l + 1][rp][bl][0];
                    xv[0] = xs[0]; xv[1] = xs[1]; xv[2] = xs[2];
                    hv[0] = hs[0]; hv[1] = hs[1]; hv[2] = hs[2];
                }

                float acc[4] = {bias[0], bias[1], bias[2], bias[3]};
                #pragma unroll
                for (int i = 0; i < H; ++i) {
                    #pragma unroll
                    for (int g = 0; g < 4; ++g) acc[g] = fmaf(wi[g][i], xin[i], acc[g]);
                }
                #pragma unroll
                for (int kk = 0; kk < H; ++kk) {
                    #pragma unroll
                    for (int g = 0; g < 4; ++g) acc[g] = fmaf(wh[g][kk], hin[kk], acc[g]);
                }

                const float ig = sigmoid_f(acc[0]);
                const float fg = sigmoid_f(acc[1]);
                const float gg = tanh_f(acc[2]);
                const float og = sigmoid_f(acc[3]);
                c = fmaf(fg, c, ig * gg);
                const float hval = og * tanh_f(c);

                buf[l + 1][wp][bl][j] = hval;

                if (l == L - 1) {
                    // t&7 == (u-1)&7 at even s0; accumulate, flush 8 at u==0
                    // (same barrier as the x-load drain).
                    hbuf[(u + CH - 1) & (CH - 1)] = hval;
                    if (u == 0 && t >= CH - 1) {
                        #pragma unroll
                        for (int i = 0; i < CH; ++i) {
                            out[(size_t)(t - (CH - 1) + i) * BH + boff] = hbuf[i];
                        }
                    }
                }
            }
            // Stage x(s+1) for layer 0's next step.
            if (l == 0 && (s + 1) < T) {
                buf[0][wp][bl][j] = xcur[u];
            }
            __syncthreads();
        }

        if (l == 0) {
            #pragma unroll
            for (int i = 0; i < CH; ++i) xcur[i] = xnext[i];
        }
    }

    // Finals: layer l's h(T-1) was written at s = T-1+l, parity (l+1)&1.
    hn[(l * B + b) * H + j] = buf[l + 1][(l + 1) & 1][bl][j];
    cn[(l * B + b) * H + j] = c;
}

} // namespace

extern "C" void kernel_launch(void* const* d_in, const int* in_sizes, int n_in,
                              void* d_out, int out_size, void* d_ws, size_t ws_size,
                              hipStream_t stream) {
    (void)in_sizes; (void)n_in; (void)d_ws; (void)ws_size; (void)out_size;
    const float* x   = (const float*)d_in[0];
    const float* hp  = (const float*)d_in[1];
    const float* cp  = (const float*)d_in[2];
    const float* Wih = (const float*)d_in[3];
    const float* Whh = (const float*)d_in[4];
    const float* bih = (const float*)d_in[5];
    const float* bhh = (const float*)d_in[6];

    float* out = (float*)d_out;
    float* hn  = out + (size_t)T * B * H;
    float* cn  = hn + (size_t)L * B * H;

    lstm_pipeline<<<dim3(B / BBLK), dim3(NTHREADS), 0, stream>>>(
        x, hp, cp, Wih, Whh, bih, bhh, out, hn, cn);
}

// Round 5
// 541.072 us; speedup vs baseline: 1.3923x; 1.0084x over previous
//
#include <hip/hip_runtime.h>

namespace {

constexpr int T = 1024;
constexpr int B = 1024;
constexpr int L = 10;
constexpr int H = 10;
constexpr int NTHREADS = 128;           // 2 full waves; 100 active threads
constexpr int NSTEP = T + L - 1;        // 1033
constexpr int BH = B * H;

using v2f = __attribute__((ext_vector_type(2))) float;

#if __has_builtin(__builtin_elementwise_fma)
__device__ __forceinline__ v2f v2fma(v2f a, v2f b, v2f c) {
    return __builtin_elementwise_fma(a, b, c);   // -> v_pk_fma_f32
}
#else
__device__ __forceinline__ v2f v2fma(v2f a, v2f b, v2f c) {
    v2f r; r[0] = fmaf(a[0], b[0], c[0]); r[1] = fmaf(a[1], b[1], c[1]); return r;
}
#endif

// v_exp-based fast activations; saturation-safe at +/-inf.
__device__ __forceinline__ float sigmoid_f(float x) {
    return __builtin_amdgcn_rcpf(1.0f + __expf(-x));
}
__device__ __forceinline__ float tanh_f(float x) {
    return 1.0f - 2.0f * __builtin_amdgcn_rcpf(1.0f + __expf(2.0f * x));
}

// waves_per_eu(2,2): pin the allocator's occupancy target at 2 waves/EU
// (256-VGPR budget) so the 84-float weight set stays resident — round-4's
// VGPR_Count=76 proved launch_bounds' 2nd arg didn't stop in-loop remat
// of the weight loads.
__global__
__attribute__((amdgpu_flat_work_group_size(NTHREADS, NTHREADS)))
__attribute__((amdgpu_waves_per_eu(2, 2)))
void lstm_pipeline(const float* __restrict__ x,    // [T,B,H]
                   const float* __restrict__ hp,   // [L,B,H]
                   const float* __restrict__ cp,   // [L,B,H]
                   const float* __restrict__ Wih,  // [L,4H,H]
                   const float* __restrict__ Whh,  // [L,4H,H]
                   const float* __restrict__ bih,  // [L,4H]
                   const float* __restrict__ bhh,  // [L,4H]
                   float* __restrict__ out,        // [T,B,H]
                   float* __restrict__ hn,         // [L,B,H]
                   float* __restrict__ cn)         // [L,B,H]
{
    // buf[l] = input to layer l (l=0: staged x; l>=1: h of layer l-1).
    // s-parity double buffer; rows padded 10->12 floats for float4 reads.
    __shared__ __align__(16) float buf[L + 1][2][12];

    const int tid = threadIdx.x;
    const bool active = tid < L * H;
    const int l = active ? tid / H : L - 1;   // layer 0..9
    const int j = active ? tid % H : H - 1;   // hidden unit 0..9
    const int b = blockIdx.x;                 // one batch element per block
    const int boff = b * H + j;

    // Per-thread weights as float2 pairs (torch gate order i,f,g,o).
    v2f wi2[4][5], wh2[4][5];
    float bias[4];
    float c = 0.0f, xa = 0.0f;

    if (active) {
        #pragma unroll
        for (int g = 0; g < 4; ++g) {
            const size_t row = (size_t)(l * 4 * H + g * H + j);
            const float* wr = Wih + row * H;
            const float* hr = Whh + row * H;
            #pragma unroll
            for (int p = 0; p < 5; ++p) {
                v2f a; a[0] = wr[2 * p]; a[1] = wr[2 * p + 1]; wi2[g][p] = a;
                v2f d; d[0] = hr[2 * p]; d[1] = hr[2 * p + 1]; wh2[g][p] = d;
            }
            bias[g] = bih[row] + bhh[row];
        }
        c = cp[(l * B + b) * H + j];
        // h(-1): layer l reads it at s=l from parity (l-1)&1.
        buf[l + 1][(l & 1) ^ 1][j] = hp[(l * B + b) * H + j];
        if (l == 0) {
            buf[0][1][j] = x[boff];          // x(0), read at s=0 (parity 1)
            xa = x[BH + boff];               // x(1), staged at s=0
        }
    }
    __syncthreads();

    auto step = [&](int s, int wp, int rp) {
        if (active) {
            const int t = s - l;
            if (t >= 0 && t < T) {
                float xin[12], hin[12];
                {
                    float4* xv = (float4*)xin;
                    float4* hv = (float4*)hin;
                    const float4* xs = (const float4*)&buf[l][rp][0];
                    const float4* hs = (const float4*)&buf[l + 1][rp][0];
                    xv[0] = xs[0]; xv[1] = xs[1]; xv[2] = xs[2];
                    hv[0] = hs[0]; hv[1] = hs[1]; hv[2] = hs[2];
                }

                v2f acc2[4];
                #pragma unroll
                for (int g = 0; g < 4; ++g) {
                    v2f a; a[0] = bias[g]; a[1] = 0.0f; acc2[g] = a;
                }
                #pragma unroll
                for (int p = 0; p < 5; ++p) {
                    v2f xp; xp[0] = xin[2 * p]; xp[1] = xin[2 * p + 1];
                    #pragma unroll
                    for (int g = 0; g < 4; ++g) acc2[g] = v2fma(wi2[g][p], xp, acc2[g]);
                }
                #pragma unroll
                for (int p = 0; p < 5; ++p) {
                    v2f hh; hh[0] = hin[2 * p]; hh[1] = hin[2 * p + 1];
                    #pragma unroll
                    for (int g = 0; g < 4; ++g) acc2[g] = v2fma(wh2[g][p], hh, acc2[g]);
                }

                const float ig = sigmoid_f(acc2[0][0] + acc2[0][1]);
                const float fg = sigmoid_f(acc2[1][0] + acc2[1][1]);
                const float gg = tanh_f(acc2[2][0] + acc2[2][1]);
                const float og = sigmoid_f(acc2[3][0] + acc2[3][1]);
                c = fmaf(fg, c, ig * gg);
                const float hval = og * tanh_f(c);

                buf[l + 1][wp][j] = hval;
                if (l == L - 1) {
                    out[(size_t)t * BH + boff] = hval;
                }
            }
            // Layer 0: stage x(s+1) (loaded one step ago), issue x(s+2).
            if (l == 0 && (s + 1) < T) {
                buf[0][wp][j] = xa;
                if ((s + 2) < T) xa = x[(size_t)(s + 2) * BH + boff];
            }
        }
        __syncthreads();
    };

    // Unroll by 2 so LDS parity indices are compile-time constants.
    for (int sb = 0; sb < NSTEP + 1; sb += 2) {   // covers s=0..1033 (1033 pads out)
        step(sb, 0, 1);
        step(sb + 1, 1, 0);
    }

    // Finals: layer l's h(T-1) was written at s=T-1+l -> parity (l+1)&1 (T even).
    if (active) {
        hn[(l * B + b) * H + j] = buf[l + 1][(l + 1) & 1][j];
        cn[(l * B + b) * H + j] = c;
    }
}

} // namespace

extern "C" void kernel_launch(void* const* d_in, const int* in_sizes, int n_in,
                              void* d_out, int out_size, void* d_ws, size_t ws_size,
                              hipStream_t stream) {
    (void)in_sizes; (void)n_in; (void)d_ws; (void)ws_size; (void)out_size;
    const float* x   = (const float*)d_in[0];
    const float* hp  = (const float*)d_in[1];
    const float* cp  = (const float*)d_in[2];
    const float* Wih = (const float*)d_in[3];
    const float* Whh = (const float*)d_in[4];
    const float* bih = (const float*)d_in[5];
    const float* bhh = (const float*)d_in[6];

    float* out = (float*)d_out;
    float* hn  = out + (size_t)T * B * H;
    float* cn  = hn + (size_t)L * B * H;

    lstm_pipeline<<<dim3(B), dim3(NTHREADS), 0, stream>>>(
        x, hp, cp, Wih, Whh, bih, bhh, out, hn, cn);
}